// Round 17
// baseline (119.976 us; speedup 1.0000x reference)
//
#include <hip/hip_runtime.h>
#include <hip/hip_bf16.h>

#define NR  8192      // rows per view
#define M   16384     // 2*NR concatenated
#define SUBB 8192     // 64 cols * 128 B (one fp8 Y sub-tile)

constexpr float INV_T   = 2.5f;                  // 1/0.4
constexpr float SCALE_S = 1.89914134f;           // sqrt(2.5*log2(e)); s^2=2.5*log2e
constexpr float E_REFL  = 12.182493960703473f;   // exp(2.5)
constexpr unsigned UNIT_E8M0 = 0x7F7F7F7Fu;      // e8m0 scale = 2^0 in all bytes

typedef int   i32x4 __attribute__((ext_vector_type(4)));
typedef int   i32x8 __attribute__((ext_vector_type(8)));
typedef float f32x4 __attribute__((ext_vector_type(4)));

typedef const __attribute__((address_space(1))) unsigned int* gas_u32;
typedef __attribute__((address_space(3))) unsigned int*       las_u32;

__device__ __forceinline__ float fexp2(float x) {
#if __has_builtin(__builtin_amdgcn_exp2f)
    return __builtin_amdgcn_exp2f(x);
#else
    return exp2f(x);
#endif
}

// Stage one 64-col (8 KB) fp8 sub-tile global->LDS with 256 threads:
// 2 x global_load_lds(16B) per thread. LDS dest linear; global src XOR-pre-
// swizzled (involution on byte bits 4..6 keyed by row&7 = bits 7..9) so
// swizzled 16B fragment reads are low-conflict.
__device__ __forceinline__ void stage_sub8(const char* __restrict__ gsrc,
                                           char* lds, int w, int lane) {
    #pragma unroll
    for (int it = 0; it < 2; ++it) {
        int off = w * 2048 + it * 1024 + lane * 16;
        int swz = off ^ (((off >> 7) & 7) << 4);
        __builtin_amdgcn_global_load_lds((gas_u32)(gsrc + swz),
                                         (las_u32)(lds + w * 2048 + it * 1024),
                                         16, 0, 0);
    }
}

// ---------------------------------------------------------------------------
// Kernel 1: L2-normalize rows; store fp8(e4m3) Z = [z1n; z2n] PRE-SCALED by
// SCALE_S (so the MX-MFMA output is directly the exp2 argument); fp32 cross
// dot; zero the rowsum array R AND the output scalar (final_kernel
// accumulates into it atomically -> re-zeroed every call for replay
// determinism).
// ---------------------------------------------------------------------------
__global__ __launch_bounds__(256) void norm_kernel(
    const float* __restrict__ outp, const float* __restrict__ augp,
    unsigned char* __restrict__ Zf8, float* __restrict__ R,
    float* __restrict__ posdot, float* __restrict__ outf)
{
    int gt = blockIdx.x * 256 + threadIdx.x;
    if (gt < M) R[gt] = 0.0f;
    if (gt == 0) outf[0] = 0.0f;

    const int w    = threadIdx.x >> 6;
    const int lane = threadIdx.x & 63;
    const int row  = blockIdx.x * 4 + w;

    float2 a = *(const float2*)(outp + row * 128 + lane * 2);
    float2 b = *(const float2*)(augp + row * 128 + lane * 2);

    float ssa = a.x * a.x + a.y * a.y;
    float ssb = b.x * b.x + b.y * b.y;
    #pragma unroll
    for (int m = 1; m < 64; m <<= 1) {
        ssa += __shfl_xor(ssa, m);
        ssb += __shfl_xor(ssb, m);
    }
    float inva = 1.0f / fmaxf(sqrtf(ssa), 1e-12f);
    float invb = 1.0f / fmaxf(sqrtf(ssb), 1e-12f);

    float xa0 = a.x * inva, xa1 = a.y * inva;   // unit-normalized (fp32)
    float xb0 = b.x * invb, xb1 = b.y * invb;

    unsigned int pa = __builtin_amdgcn_cvt_pk_fp8_f32(xa0 * SCALE_S, xa1 * SCALE_S, 0, false);
    unsigned int pb = __builtin_amdgcn_cvt_pk_fp8_f32(xb0 * SCALE_S, xb1 * SCALE_S, 0, false);
    *(unsigned short*)(Zf8 + (size_t)row * 128 + lane * 2)        = (unsigned short)pa;
    *(unsigned short*)(Zf8 + (size_t)(NR + row) * 128 + lane * 2) = (unsigned short)pb;

    float d = xa0 * xb0 + xa1 * xb1;   // positive-pair dot stays fp32-exact
    #pragma unroll
    for (int m = 1; m < 64; m <<= 1) d += __shfl_xor(d, m);
    if (lane == 0) posdot[row] = d;
}

// ---------------------------------------------------------------------------
// Kernel 2: row sums of exp2(Zs Zs^T) via MX-fp8 K=128 MFMA — R12/R16
// structure with DOUBLED A-reuse (rt=8): wave owns 128 rows, so each
// B-fragment LDS read feeds 8 MFMAs (halves the LDS-read pipe 13 -> 6.5 us
// and the per-output ct-loop overhead).  Block = 256 thr / 4 waves owns 512
// rows; grid (32 col-chunks, 32 row-blocks) = 1024 blocks = 4/CU of work.
// Registers: afrag[8] 64 + rs[8] 32 + operands ~20 ~= 115 < 128 cap at
// launch_bounds(256,4) — no spill (R11/R13 lesson: check VGPR_Count first).
// Per ct (16 cols): 2 swizzled 16B LDS reads (lane-constant addresses) ->
// b8 -> 8 MFMA (rt) -> 32 exp2 -> 32 adds.  Y chunk = 512 cols = 8 subtiles
// of 64 cols (8 KB), double-buffered via global_load_lds.  id%8 = ch%8 pins
// 4 chunks/XCD (Y set 256 KB + Z 2 MB fit the 4 MB XCD L2).
// ---------------------------------------------------------------------------
__global__ __launch_bounds__(256, 4) void gram_kernel(
    const unsigned char* __restrict__ Zf8, float* __restrict__ R)
{
    __shared__ char buf[2][SUBB];   // 16 KB

    const int tid  = threadIdx.x;
    const int w    = tid >> 6;       // 0..3
    const int lane = tid & 63;
    const int l16  = lane & 15;
    const int lg   = lane >> 4;      // 0..3 (32-byte k-chunk)
    const int ch   = blockIdx.x;     // 0..31 (512 cols each)
    const int rb   = blockIdx.y;     // 0..31 (512 rows each)

    const char* Zb = (const char*)Zf8;
    const char* Xg = Zb + (size_t)rb * 65536;     // 512 rows * 128 B
    const char* Yg = Zb + (size_t)ch * 65536;     // 512 cols * 128 B

    // A fragments: 128 rows per wave, full K=128 (32 B/lane), one-time read
    i32x8 afrag[8];
    #pragma unroll
    for (int rt = 0; rt < 8; ++rt)
        afrag[rt] = *(const i32x8*)(Xg + (w * 128 + rt * 16 + l16) * 128 + lg * 32);

    stage_sub8(Yg, buf[0], w, lane);
    __syncthreads();

    f32x4 rs[8];
    #pragma unroll
    for (int rt = 0; rt < 8; ++rt) rs[rt] = (f32x4){0.f, 0.f, 0.f, 0.f};
    const f32x4 zero4 = (f32x4){0.f, 0.f, 0.f, 0.f};

    // precomputed lane-constant LDS read offsets (ct adds bits >= 11 only)
    const int key   = (l16 & 7) << 4;
    const int lbase = l16 * 128 + lg * 32;
    const int addrA = lbase ^ key;
    const int addrB = (lbase + 16) ^ key;

    #pragma unroll 1
    for (int s = 0; s < 8; ++s) {
        if (s + 1 < 8)
            stage_sub8(Yg + (size_t)(s + 1) * SUBB, buf[(s + 1) & 1], w, lane);

        const char* cur = buf[s & 1];

        #pragma unroll
        for (int ct = 0; ct < 4; ++ct) {
            i32x4 lo = *(const i32x4*)(cur + ct * 2048 + addrA);
            i32x4 hi = *(const i32x4*)(cur + ct * 2048 + addrB);
            i32x8 b8 = {lo[0], lo[1], lo[2], lo[3], hi[0], hi[1], hi[2], hi[3]};
            #pragma unroll
            for (int rt = 0; rt < 8; ++rt) {
                f32x4 d = __builtin_amdgcn_mfma_scale_f32_16x16x128_f8f6f4(
                    afrag[rt], b8, zero4,
                    0 /*fmtA=fp8*/, 0 /*fmtB=fp8*/,
                    0, UNIT_E8M0, 0, UNIT_E8M0);
                f32x4 e;
                e[0] = fexp2(d[0]); e[1] = fexp2(d[1]);
                e[2] = fexp2(d[2]); e[3] = fexp2(d[3]);
                rs[rt] += e;
            }
        }
        __syncthreads();   // stage(s+1) landed + all waves done with cur
    }

    // reduce row sums across the 16 lanes holding one row's columns
    #pragma unroll
    for (int rt = 0; rt < 8; ++rt)
        #pragma unroll
        for (int q = 0; q < 4; ++q) {
            float v = rs[rt][q];
            v += __shfl_xor(v, 1);  v += __shfl_xor(v, 2);
            v += __shfl_xor(v, 4);  v += __shfl_xor(v, 8);
            if (l16 == 0)
                atomicAdd(&R[rb * 512 + w * 128 + rt * 16 + lg * 4 + q], v);
        }
}

// ---------------------------------------------------------------------------
// Kernel 3: loss = mean_i [ -dot_i/tau + 0.5(log(R_i - E) + log(R_{NR+i} - E)) ]
// 32 blocks x 256 thr (1 row/thread), wave-shuffle reduce + one atomicAdd
// per wave into outf (zeroed by norm_kernel each call).
// ---------------------------------------------------------------------------
__global__ __launch_bounds__(256) void final_kernel(
    const float* __restrict__ R, const float* __restrict__ posdot,
    float* __restrict__ outv)
{
    const int i = blockIdx.x * 256 + threadIdx.x;   // 0..8191
    float d1 = R[i]      - E_REFL;
    float d2 = R[NR + i] - E_REFL;
    float local = -posdot[i] * INV_T + 0.5f * (logf(d1) + logf(d2));

    #pragma unroll
    for (int m = 1; m < 64; m <<= 1) local += __shfl_xor(local, m);
    if ((threadIdx.x & 63) == 0)
        atomicAdd(outv, local * (1.0f / NR));
}

// ---------------------------------------------------------------------------
extern "C" void kernel_launch(void* const* d_in, const int* in_sizes, int n_in,
                              void* d_out, int out_size, void* d_ws, size_t ws_size,
                              hipStream_t stream) {
    const float* outp = (const float*)d_in[0];
    const float* augp = (const float*)d_in[1];

    char* ws = (char*)d_ws;
    unsigned char* Zf8 = (unsigned char*)ws;                  // 2 MB fp8 [16384][128]
    float* R      = (float*)(ws + 2097152);                   // 16384 f32 row sums
    float* posdot = (float*)(ws + 2097152 + 65536);           // 8192 f32
    float* outf   = (float*)d_out;

    hipLaunchKernelGGL(norm_kernel, dim3(2048), dim3(256), 0, stream,
                       outp, augp, Zf8, R, posdot, outf);

    hipLaunchKernelGGL(gram_kernel, dim3(32, 32), dim3(256), 0, stream,
                       Zf8, R);

    hipLaunchKernelGGL(final_kernel, dim3(32), dim3(256), 0, stream,
                       R, posdot, outf);
}

// Round 18
// 58.078 us; speedup vs baseline: 2.0658x; 2.0658x over previous
//
#include <hip/hip_runtime.h>
#include <hip/hip_bf16.h>

#define NR  8192      // rows per view
#define M   16384     // 2*NR concatenated
#define SUBB 8192     // 64 cols * 128 B (one fp8 Y sub-tile)

constexpr float INV_T   = 2.5f;                  // 1/0.4
constexpr float SCALE_S = 1.89914134f;           // sqrt(2.5*log2(e)); s^2=2.5*log2e
constexpr float E_REFL  = 12.182493960703473f;   // exp(2.5)
constexpr unsigned UNIT_E8M0 = 0x7F7F7F7Fu;      // e8m0 scale = 2^0 in all bytes

typedef int   i32x4 __attribute__((ext_vector_type(4)));
typedef int   i32x8 __attribute__((ext_vector_type(8)));
typedef float f32x4 __attribute__((ext_vector_type(4)));

typedef const __attribute__((address_space(1))) unsigned int* gas_u32;
typedef __attribute__((address_space(3))) unsigned int*       las_u32;

__device__ __forceinline__ float fexp2(float x) {
#if __has_builtin(__builtin_amdgcn_exp2f)
    return __builtin_amdgcn_exp2f(x);
#else
    return exp2f(x);
#endif
}

// Stage one 64-col (8 KB) fp8 sub-tile global->LDS with 256 threads:
// 2 x global_load_lds(16B) per thread. LDS dest linear; global src XOR-pre-
// swizzled (involution on byte bits 4..6 keyed by row&7 = bits 7..9) so
// swizzled 16B fragment reads are low-conflict.
__device__ __forceinline__ void stage_sub8(const char* __restrict__ gsrc,
                                           char* lds, int w, int lane) {
    #pragma unroll
    for (int it = 0; it < 2; ++it) {
        int off = w * 2048 + it * 1024 + lane * 16;
        int swz = off ^ (((off >> 7) & 7) << 4);
        __builtin_amdgcn_global_load_lds((gas_u32)(gsrc + swz),
                                         (las_u32)(lds + w * 2048 + it * 1024),
                                         16, 0, 0);
    }
}

// ---------------------------------------------------------------------------
// Kernel 1: L2-normalize rows; store fp8(e4m3) Z = [z1n; z2n] PRE-SCALED by
// SCALE_S (so the MX-MFMA output is directly the exp2 argument); fp32 cross
// dot; zero the rowsum array R AND the output scalar (final_kernel
// accumulates into it atomically -> re-zeroed every call for replay
// determinism).
// ---------------------------------------------------------------------------
__global__ __launch_bounds__(256) void norm_kernel(
    const float* __restrict__ outp, const float* __restrict__ augp,
    unsigned char* __restrict__ Zf8, float* __restrict__ R,
    float* __restrict__ posdot, float* __restrict__ outf)
{
    int gt = blockIdx.x * 256 + threadIdx.x;
    if (gt < M) R[gt] = 0.0f;
    if (gt == 0) outf[0] = 0.0f;

    const int w    = threadIdx.x >> 6;
    const int lane = threadIdx.x & 63;
    const int row  = blockIdx.x * 4 + w;

    float2 a = *(const float2*)(outp + row * 128 + lane * 2);
    float2 b = *(const float2*)(augp + row * 128 + lane * 2);

    float ssa = a.x * a.x + a.y * a.y;
    float ssb = b.x * b.x + b.y * b.y;
    #pragma unroll
    for (int m = 1; m < 64; m <<= 1) {
        ssa += __shfl_xor(ssa, m);
        ssb += __shfl_xor(ssb, m);
    }
    float inva = 1.0f / fmaxf(sqrtf(ssa), 1e-12f);
    float invb = 1.0f / fmaxf(sqrtf(ssb), 1e-12f);

    float xa0 = a.x * inva, xa1 = a.y * inva;   // unit-normalized (fp32)
    float xb0 = b.x * invb, xb1 = b.y * invb;

    unsigned int pa = __builtin_amdgcn_cvt_pk_fp8_f32(xa0 * SCALE_S, xa1 * SCALE_S, 0, false);
    unsigned int pb = __builtin_amdgcn_cvt_pk_fp8_f32(xb0 * SCALE_S, xb1 * SCALE_S, 0, false);
    *(unsigned short*)(Zf8 + (size_t)row * 128 + lane * 2)        = (unsigned short)pa;
    *(unsigned short*)(Zf8 + (size_t)(NR + row) * 128 + lane * 2) = (unsigned short)pb;

    float d = xa0 * xb0 + xa1 * xb1;   // positive-pair dot stays fp32-exact
    #pragma unroll
    for (int m = 1; m < 64; m <<= 1) d += __shfl_xor(d, m);
    if (lane == 0) posdot[row] = d;
}

// ---------------------------------------------------------------------------
// Kernel 2: row sums of exp2(Zs Zs^T) via MX-fp8 K=128 MFMA — rt=8 (wave
// owns 128 rows), RETRY with the register cap released:
// __launch_bounds__(256, 2) allows up to 256 arch-VGPRs/wave.  R17's
// (256,4) silently capped arch-VGPRs at 64 (unified VGPR/AGPR budget split)
// and spilled afrag+acc to scratch (VGPR_Count 64, FETCH 267 MB, 114 us).
// Expected allocation ~130-150 VGPR -> 3 waves/SIMD residency (512/140) =
// 12 waves/CU — same occupancy as R16's measured 37%, but each B-fragment
// LDS read now feeds 8 MFMAs: LDS-read pipe 13 -> 6.5 us, staging traffic
// and barrier count per output halved.
// Block = 256 thr / 4 waves owns 512 rows; grid (32 col-chunks, 32
// row-blocks) = 1024 blocks = 4/CU of work.  Y chunk = 512 cols = 8
// subtiles of 64 cols (8 KB), double-buffered via global_load_lds.
// Per ct (16 cols): 2 swizzled 16B LDS reads (lane-constant addresses) ->
// b8 -> 8 MFMA (rt) -> 32 exp2 -> 32 adds.  id%8 = ch%8 pins 4 chunks/XCD.
// ---------------------------------------------------------------------------
__global__ __launch_bounds__(256, 2) void gram_kernel(
    const unsigned char* __restrict__ Zf8, float* __restrict__ R)
{
    __shared__ char buf[2][SUBB];   // 16 KB

    const int tid  = threadIdx.x;
    const int w    = tid >> 6;       // 0..3
    const int lane = tid & 63;
    const int l16  = lane & 15;
    const int lg   = lane >> 4;      // 0..3 (32-byte k-chunk)
    const int ch   = blockIdx.x;     // 0..31 (512 cols each)
    const int rb   = blockIdx.y;     // 0..31 (512 rows each)

    const char* Zb = (const char*)Zf8;
    const char* Xg = Zb + (size_t)rb * 65536;     // 512 rows * 128 B
    const char* Yg = Zb + (size_t)ch * 65536;     // 512 cols * 128 B

    // A fragments: 128 rows per wave, full K=128 (32 B/lane), one-time read
    i32x8 afrag[8];
    #pragma unroll
    for (int rt = 0; rt < 8; ++rt)
        afrag[rt] = *(const i32x8*)(Xg + (w * 128 + rt * 16 + l16) * 128 + lg * 32);

    stage_sub8(Yg, buf[0], w, lane);
    __syncthreads();

    f32x4 rs[8];
    #pragma unroll
    for (int rt = 0; rt < 8; ++rt) rs[rt] = (f32x4){0.f, 0.f, 0.f, 0.f};
    const f32x4 zero4 = (f32x4){0.f, 0.f, 0.f, 0.f};

    // precomputed lane-constant LDS read offsets (ct adds bits >= 11 only)
    const int key   = (l16 & 7) << 4;
    const int lbase = l16 * 128 + lg * 32;
    const int addrA = lbase ^ key;
    const int addrB = (lbase + 16) ^ key;

    #pragma unroll 1
    for (int s = 0; s < 8; ++s) {
        if (s + 1 < 8)
            stage_sub8(Yg + (size_t)(s + 1) * SUBB, buf[(s + 1) & 1], w, lane);

        const char* cur = buf[s & 1];

        #pragma unroll
        for (int ct = 0; ct < 4; ++ct) {
            i32x4 lo = *(const i32x4*)(cur + ct * 2048 + addrA);
            i32x4 hi = *(const i32x4*)(cur + ct * 2048 + addrB);
            i32x8 b8 = {lo[0], lo[1], lo[2], lo[3], hi[0], hi[1], hi[2], hi[3]};
            #pragma unroll
            for (int rt = 0; rt < 8; ++rt) {
                f32x4 d = __builtin_amdgcn_mfma_scale_f32_16x16x128_f8f6f4(
                    afrag[rt], b8, zero4,
                    0 /*fmtA=fp8*/, 0 /*fmtB=fp8*/,
                    0, UNIT_E8M0, 0, UNIT_E8M0);
                f32x4 e;
                e[0] = fexp2(d[0]); e[1] = fexp2(d[1]);
                e[2] = fexp2(d[2]); e[3] = fexp2(d[3]);
                rs[rt] += e;
            }
        }
        __syncthreads();   // stage(s+1) landed + all waves done with cur
    }

    // reduce row sums across the 16 lanes holding one row's columns
    #pragma unroll
    for (int rt = 0; rt < 8; ++rt)
        #pragma unroll
        for (int q = 0; q < 4; ++q) {
            float v = rs[rt][q];
            v += __shfl_xor(v, 1);  v += __shfl_xor(v, 2);
            v += __shfl_xor(v, 4);  v += __shfl_xor(v, 8);
            if (l16 == 0)
                atomicAdd(&R[rb * 512 + w * 128 + rt * 16 + lg * 4 + q], v);
        }
}

// ---------------------------------------------------------------------------
// Kernel 3: loss = mean_i [ -dot_i/tau + 0.5(log(R_i - E) + log(R_{NR+i} - E)) ]
// 32 blocks x 256 thr (1 row/thread), wave-shuffle reduce + one atomicAdd
// per wave into outf (zeroed by norm_kernel each call).
// ---------------------------------------------------------------------------
__global__ __launch_bounds__(256) void final_kernel(
    const float* __restrict__ R, const float* __restrict__ posdot,
    float* __restrict__ outv)
{
    const int i = blockIdx.x * 256 + threadIdx.x;   // 0..8191
    float d1 = R[i]      - E_REFL;
    float d2 = R[NR + i] - E_REFL;
    float local = -posdot[i] * INV_T + 0.5f * (logf(d1) + logf(d2));

    #pragma unroll
    for (int m = 1; m < 64; m <<= 1) local += __shfl_xor(local, m);
    if ((threadIdx.x & 63) == 0)
        atomicAdd(outv, local * (1.0f / NR));
}

// ---------------------------------------------------------------------------
extern "C" void kernel_launch(void* const* d_in, const int* in_sizes, int n_in,
                              void* d_out, int out_size, void* d_ws, size_t ws_size,
                              hipStream_t stream) {
    const float* outp = (const float*)d_in[0];
    const float* augp = (const float*)d_in[1];

    char* ws = (char*)d_ws;
    unsigned char* Zf8 = (unsigned char*)ws;                  // 2 MB fp8 [16384][128]
    float* R      = (float*)(ws + 2097152);                   // 16384 f32 row sums
    float* posdot = (float*)(ws + 2097152 + 65536);           // 8192 f32
    float* outf   = (float*)d_out;

    hipLaunchKernelGGL(norm_kernel, dim3(2048), dim3(256), 0, stream,
                       outp, augp, Zf8, R, posdot, outf);

    hipLaunchKernelGGL(gram_kernel, dim3(32, 32), dim3(256), 0, stream,
                       Zf8, R);

    hipLaunchKernelGGL(final_kernel, dim3(32), dim3(256), 0, stream,
                       R, posdot, outf);
}

// Round 19
// 52.734 us; speedup vs baseline: 2.2751x; 1.1013x over previous
//
#include <hip/hip_runtime.h>
#include <hip/hip_bf16.h>

#define NR  8192      // rows per view
#define M   16384     // 2*NR concatenated
#define SUBB 16384    // 128 cols * 128 B (one fp8 Y sub-tile)

constexpr float INV_T   = 2.5f;                  // 1/0.4
constexpr float SCALE_S = 1.89914134f;           // sqrt(2.5*log2(e)); s^2=2.5*log2e
constexpr float E_REFL  = 12.182493960703473f;   // exp(2.5)
constexpr unsigned UNIT_E8M0 = 0x7F7F7F7Fu;      // e8m0 scale = 2^0 in all bytes

typedef int   i32x4 __attribute__((ext_vector_type(4)));
typedef int   i32x8 __attribute__((ext_vector_type(8)));
typedef float f32x4 __attribute__((ext_vector_type(4)));

typedef const __attribute__((address_space(1))) unsigned int* gas_u32;
typedef __attribute__((address_space(3))) unsigned int*       las_u32;

__device__ __forceinline__ float fexp2(float x) {
#if __has_builtin(__builtin_amdgcn_exp2f)
    return __builtin_amdgcn_exp2f(x);
#else
    return exp2f(x);
#endif
}

// Stage one 128-col (16 KB) fp8 sub-tile global->LDS with 256 threads:
// 4 x global_load_lds(16B) per thread. LDS dest linear; global src XOR-pre-
// swizzled (involution on byte bits 4..6 keyed by row&7 = bits 7..9) so
// swizzled 16B fragment reads are low-conflict.
__device__ __forceinline__ void stage_sub16(const char* __restrict__ gsrc,
                                            char* lds, int w, int lane) {
    #pragma unroll
    for (int it = 0; it < 4; ++it) {
        int off = w * 4096 + it * 1024 + lane * 16;
        int swz = off ^ (((off >> 7) & 7) << 4);
        __builtin_amdgcn_global_load_lds((gas_u32)(gsrc + swz),
                                         (las_u32)(lds + w * 4096 + it * 1024),
                                         16, 0, 0);
    }
}

// ---------------------------------------------------------------------------
// Kernel 1: L2-normalize rows; store fp8(e4m3) Z = [z1n; z2n] PRE-SCALED by
// SCALE_S (so the MX-MFMA output is directly the exp2 argument); fp32 cross
// dot; zero the rowsum array R AND the output scalar (final_kernel
// accumulates atomically -> re-zeroed every call for replay determinism).
// ---------------------------------------------------------------------------
__global__ __launch_bounds__(256) void norm_kernel(
    const float* __restrict__ outp, const float* __restrict__ augp,
    unsigned char* __restrict__ Zf8, float* __restrict__ R,
    float* __restrict__ posdot, float* __restrict__ outf)
{
    int gt = blockIdx.x * 256 + threadIdx.x;
    if (gt < M) R[gt] = 0.0f;
    if (gt == 0) outf[0] = 0.0f;

    const int w    = threadIdx.x >> 6;
    const int lane = threadIdx.x & 63;
    const int row  = blockIdx.x * 4 + w;

    float2 a = *(const float2*)(outp + row * 128 + lane * 2);
    float2 b = *(const float2*)(augp + row * 128 + lane * 2);

    float ssa = a.x * a.x + a.y * a.y;
    float ssb = b.x * b.x + b.y * b.y;
    #pragma unroll
    for (int m = 1; m < 64; m <<= 1) {
        ssa += __shfl_xor(ssa, m);
        ssb += __shfl_xor(ssb, m);
    }
    float inva = 1.0f / fmaxf(sqrtf(ssa), 1e-12f);
    float invb = 1.0f / fmaxf(sqrtf(ssb), 1e-12f);

    float xa0 = a.x * inva, xa1 = a.y * inva;   // unit-normalized (fp32)
    float xb0 = b.x * invb, xb1 = b.y * invb;

    unsigned int pa = __builtin_amdgcn_cvt_pk_fp8_f32(xa0 * SCALE_S, xa1 * SCALE_S, 0, false);
    unsigned int pb = __builtin_amdgcn_cvt_pk_fp8_f32(xb0 * SCALE_S, xb1 * SCALE_S, 0, false);
    *(unsigned short*)(Zf8 + (size_t)row * 128 + lane * 2)        = (unsigned short)pa;
    *(unsigned short*)(Zf8 + (size_t)(NR + row) * 128 + lane * 2) = (unsigned short)pb;

    float d = xa0 * xb0 + xa1 * xb1;   // positive-pair dot stays fp32-exact
    #pragma unroll
    for (int m = 1; m < 64; m <<= 1) d += __shfl_xor(d, m);
    if (lane == 0) posdot[row] = d;
}

// ---------------------------------------------------------------------------
// Kernel 2: row sums of exp2(Zs Zs^T) via MX-fp8 K=128 MFMA.
// R16 structure (best: 47.5 us) + two micro-fixes:
//  (1) subtile 64 -> 128 cols (16 KB, dbuf 32 KB): 5 barriers/block instead
//      of 9; doubled inter-barrier compute runs for wave de-phasing.
//  (2) b8 operand built via subvector writes of the two ds_read_b128
//      results (no 8-element initializer) — removes up to 8 v_mov/ct from
//      the binding VALU pipe.
// Grid (32 col-chunks, 64 row-blocks) = 2048 blocks; launch_bounds(256,4)
// -> VGPR ~44-50, rt=4 live-range profile (R13 lesson: unroll 1 over
// ct-quads bounds live B-operands).  Wave owns 64 rows (afrag[4], full
// K=128, 32 B/lane, one-time L2 read).  Per ct: 2 swizzled 16B LDS reads
// (lane-constant addresses; ct adds bits >= 11 only) -> b8 -> 4 MFMA (rt)
// -> 16 exp2 -> 16 adds.  id%8 = ch%8 pins 4 chunks/XCD.
// Falsified alternatives: rt=8 both reg-regimes (R17 spill, R18 occupancy),
// symmetry (R3/R10 atomics+locality), direct-L2 B (R8 latency), counted
// vmcnt/self-paced/single-shot overlap variants (R7/R14/R15).
// ---------------------------------------------------------------------------
__global__ __launch_bounds__(256, 4) void gram_kernel(
    const unsigned char* __restrict__ Zf8, float* __restrict__ R)
{
    __shared__ char buf[2][SUBB];   // 32 KB

    const int tid  = threadIdx.x;
    const int w    = tid >> 6;       // 0..3
    const int lane = tid & 63;
    const int l16  = lane & 15;
    const int lg   = lane >> 4;      // 0..3 (32-byte k-chunk)
    const int ch   = blockIdx.x;     // 0..31 (512 cols each)
    const int rb   = blockIdx.y;     // 0..63 (256 rows each)

    const char* Zb = (const char*)Zf8;
    const char* Xg = Zb + (size_t)rb * 32768;     // 256 rows * 128 B
    const char* Yg = Zb + (size_t)ch * 65536;     // 512 cols * 128 B

    // A fragments: 64 rows per wave, full K=128 (32 B/lane), one-time read
    i32x8 afrag[4];
    #pragma unroll
    for (int rt = 0; rt < 4; ++rt)
        afrag[rt] = *(const i32x8*)(Xg + (w * 64 + rt * 16 + l16) * 128 + lg * 32);

    stage_sub16(Yg, buf[0], w, lane);
    __syncthreads();

    f32x4 rs[4];
    #pragma unroll
    for (int rt = 0; rt < 4; ++rt) rs[rt] = (f32x4){0.f, 0.f, 0.f, 0.f};
    const f32x4 zero4 = (f32x4){0.f, 0.f, 0.f, 0.f};

    // precomputed lane-constant LDS read offsets (ct adds bits >= 11 only)
    const int key   = (l16 & 7) << 4;
    const int lbase = l16 * 128 + lg * 32;
    const int addrA = lbase ^ key;
    const int addrB = (lbase + 16) ^ key;

    #pragma unroll 1
    for (int s = 0; s < 4; ++s) {
        if (s + 1 < 4)
            stage_sub16(Yg + (size_t)(s + 1) * SUBB, buf[(s + 1) & 1], w, lane);

        const char* cur = buf[s & 1];

        #pragma unroll 1
        for (int cb = 0; cb < 2; ++cb) {
            #pragma unroll
            for (int ct = 0; ct < 4; ++ct) {
                const char* p = cur + (cb * 4 + ct) * 2048;
                i32x8 b8;
                *(i32x4*)&b8       = *(const i32x4*)(p + addrA);
                *((i32x4*)&b8 + 1) = *(const i32x4*)(p + addrB);
                #pragma unroll
                for (int rt = 0; rt < 4; ++rt) {
                    f32x4 d = __builtin_amdgcn_mfma_scale_f32_16x16x128_f8f6f4(
                        afrag[rt], b8, zero4,
                        0 /*fmtA=fp8*/, 0 /*fmtB=fp8*/,
                        0, UNIT_E8M0, 0, UNIT_E8M0);
                    f32x4 e;
                    e[0] = fexp2(d[0]); e[1] = fexp2(d[1]);
                    e[2] = fexp2(d[2]); e[3] = fexp2(d[3]);
                    rs[rt] += e;
                }
            }
        }
        __syncthreads();   // stage(s+1) landed + all waves done with cur
    }

    // reduce row sums across the 16 lanes holding one row's columns
    #pragma unroll
    for (int rt = 0; rt < 4; ++rt)
        #pragma unroll
        for (int q = 0; q < 4; ++q) {
            float v = rs[rt][q];
            v += __shfl_xor(v, 1);  v += __shfl_xor(v, 2);
            v += __shfl_xor(v, 4);  v += __shfl_xor(v, 8);
            if (l16 == 0)
                atomicAdd(&R[rb * 256 + w * 64 + rt * 16 + lg * 4 + q], v);
        }
}

// ---------------------------------------------------------------------------
// Kernel 3: loss = mean_i [ -dot_i/tau + 0.5(log(R_i - E) + log(R_{NR+i} - E)) ]
// 32 blocks x 256 thr (1 row/thread), wave-shuffle reduce + one atomicAdd
// per wave into outf (zeroed by norm_kernel each call).
// ---------------------------------------------------------------------------
__global__ __launch_bounds__(256) void final_kernel(
    const float* __restrict__ R, const float* __restrict__ posdot,
    float* __restrict__ outv)
{
    const int i = blockIdx.x * 256 + threadIdx.x;   // 0..8191
    float d1 = R[i]      - E_REFL;
    float d2 = R[NR + i] - E_REFL;
    float local = -posdot[i] * INV_T + 0.5f * (logf(d1) + logf(d2));

    #pragma unroll
    for (int m = 1; m < 64; m <<= 1) local += __shfl_xor(local, m);
    if ((threadIdx.x & 63) == 0)
        atomicAdd(outv, local * (1.0f / NR));
}

// ---------------------------------------------------------------------------
extern "C" void kernel_launch(void* const* d_in, const int* in_sizes, int n_in,
                              void* d_out, int out_size, void* d_ws, size_t ws_size,
                              hipStream_t stream) {
    const float* outp = (const float*)d_in[0];
    const float* augp = (const float*)d_in[1];

    char* ws = (char*)d_ws;
    unsigned char* Zf8 = (unsigned char*)ws;                  // 2 MB fp8 [16384][128]
    float* R      = (float*)(ws + 2097152);                   // 16384 f32 row sums
    float* posdot = (float*)(ws + 2097152 + 65536);           // 8192 f32
    float* outf   = (float*)d_out;

    hipLaunchKernelGGL(norm_kernel, dim3(2048), dim3(256), 0, stream,
                       outp, augp, Zf8, R, posdot, outf);

    hipLaunchKernelGGL(gram_kernel, dim3(32, 64), dim3(256), 0, stream,
                       Zf8, R);

    hipLaunchKernelGGL(final_kernel, dim3(32), dim3(256), 0, stream,
                       R, posdot, outf);
}